// Round 8
// baseline (782.084 us; speedup 1.0000x reference)
//
#include <hip/hip_runtime.h>
#include <math.h>

#define N_NODES 50000
#define N_EDGES 1600000

__device__ __forceinline__ float lrelu02(float x) { return x > 0.f ? x : 0.2f * x; }
__device__ __forceinline__ float elu1(float x)    { return x > 0.f ? x : __expf(x) - 1.f; }

// bf16 helpers (RNE pack)
__device__ __forceinline__ unsigned short f2bf(float f) {
    unsigned int u = __float_as_uint(f);
    return (unsigned short)((u + 0x7fffu + ((u >> 16) & 1u)) >> 16);
}
__device__ __forceinline__ float bf2f(unsigned short s) {
    return __uint_as_float((unsigned int)s << 16);
}
__device__ __forceinline__ float2 bfp2(unsigned int u) {
    float2 r;
    r.x = __uint_as_float(u << 16);
    r.y = __uint_as_float(u & 0xffff0000u);
    return r;
}

// ------- GEMM layers 1/2 (FOUT=64) fused with attention logits -------
template<int FIN>
__global__ void gemm_al_kernel(const float* __restrict__ x, const float* __restrict__ W,
                               const float* __restrict__ a_s, const float* __restrict__ a_d,
                               unsigned short* __restrict__ h,
                               float* __restrict__ al_s, float* __restrict__ al_d) {
    __shared__ float Wl[FIN][64];
    __shared__ unsigned short ot[32][66];   // +2 pad: LDS rows stride 33 dwords
    const int tx = threadIdx.x, ty = threadIdx.y;
    const int tid = ty * 64 + tx;
    for (int i = tid; i < FIN * 64; i += 256) {
        int k = i >> 6, f = i & 63;
        Wl[k][f] = W[(size_t)k * 64 + f];
    }
    __syncthreads();
    const int n0b = blockIdx.x * 32;
    const int n0 = n0b + ty * 8;
    float acc[8] = {0.f, 0.f, 0.f, 0.f, 0.f, 0.f, 0.f, 0.f};
    if (n0 + 8 <= N_NODES) {
        for (int k = 0; k < FIN; k += 4) {
            float4 xv[8];
#pragma unroll
            for (int i = 0; i < 8; ++i)
                xv[i] = *(const float4*)(x + (size_t)(n0 + i) * FIN + k);
#pragma unroll
            for (int kk = 0; kk < 4; ++kk) {
                float w = Wl[k + kk][tx];
#pragma unroll
                for (int i = 0; i < 8; ++i) {
                    float xs = (kk == 0) ? xv[i].x : (kk == 1) ? xv[i].y : (kk == 2) ? xv[i].z : xv[i].w;
                    acc[i] = fmaf(xs, w, acc[i]);
                }
            }
        }
    } else {
        for (int i = 0; i < 8; ++i) {
            if (n0 + i >= N_NODES) break;
            const float* xr = x + (size_t)(n0 + i) * FIN;
            float a = 0.f;
            for (int k = 0; k < FIN; ++k) a = fmaf(xr[k], Wl[k][tx], a);
            acc[i] = a;
        }
    }
#pragma unroll
    for (int i = 0; i < 8; ++i) ot[ty * 8 + i][tx] = f2bf(acc[i]);
    __syncthreads();
    int vrows = N_NODES - n0b; if (vrows > 32) vrows = 32;
    {
        unsigned int* ph = (unsigned int*)(h + (size_t)n0b * 64);
        for (int i = tid; i < vrows * 32; i += 256) {
            int row = i >> 5, col = i & 31;
            ph[i] = *(const unsigned int*)&ot[row][col * 2];
        }
    }
    if (tid < 128) {
        int node = tid >> 2, hd = tid & 3;
        if (node < vrows) {
            const float* as = a_s + hd * 16;
            const float* ad = a_d + hd * 16;
            float s1 = 0.f, s2 = 0.f;
#pragma unroll
            for (int c = 0; c < 16; c += 2) {
                unsigned int q = *(const unsigned int*)&ot[node][hd * 16 + c];
                float2 p = bfp2(q);
                s1 = fmaf(p.x, as[c], s1);     s2 = fmaf(p.x, ad[c], s2);
                s1 = fmaf(p.y, as[c + 1], s1); s2 = fmaf(p.y, ad[c + 1], s2);
            }
            al_s[(n0b + node) * 4 + hd] = s1;
            al_d[(n0b + node) * 4 + hd] = s2;
        }
    }
}

// ------- L3 GEMM: h[n,240] = bf16(x[n,64] @ W[64,240]), fused al3 -------
__global__ void gemm240_kernel(const float* __restrict__ x, const float* __restrict__ W,
                               const float* __restrict__ a_s, const float* __restrict__ a_d,
                               unsigned short* __restrict__ h,
                               float* __restrict__ al_s, float* __restrict__ al_d) {
    __shared__ float Wl[64][240];           // 61440 B
    __shared__ unsigned short ot[32][240];  // 15360 B
    const int tx = threadIdx.x, ty = threadIdx.y;
    const int tid = ty * 64 + tx;
    {
        const float4* W4 = (const float4*)W;
        float4* Wl4 = (float4*)&Wl[0][0];
        for (int i = tid; i < 64 * 240 / 4; i += 256) Wl4[i] = W4[i];
    }
    __syncthreads();
    const int n0b = blockIdx.x * 32;
    const int n0 = n0b + ty * 8;
    float acc[4][8];
#pragma unroll
    for (int g = 0; g < 4; ++g)
#pragma unroll
        for (int i = 0; i < 8; ++i) acc[g][i] = 0.f;
    const int tx3 = (tx < 48) ? (192 + tx) : 0;
    if (n0 + 8 <= N_NODES) {
        for (int k = 0; k < 64; k += 4) {
            float4 xv[8];
#pragma unroll
            for (int i = 0; i < 8; ++i)
                xv[i] = *(const float4*)(x + (size_t)(n0 + i) * 64 + k);
#pragma unroll
            for (int kk = 0; kk < 4; ++kk) {
                float w0 = Wl[k + kk][tx];
                float w1 = Wl[k + kk][64 + tx];
                float w2 = Wl[k + kk][128 + tx];
                float w3 = Wl[k + kk][tx3];
#pragma unroll
                for (int i = 0; i < 8; ++i) {
                    float xs = (kk == 0) ? xv[i].x : (kk == 1) ? xv[i].y : (kk == 2) ? xv[i].z : xv[i].w;
                    acc[0][i] = fmaf(xs, w0, acc[0][i]);
                    acc[1][i] = fmaf(xs, w1, acc[1][i]);
                    acc[2][i] = fmaf(xs, w2, acc[2][i]);
                    acc[3][i] = fmaf(xs, w3, acc[3][i]);
                }
            }
        }
    } else {
        for (int i = 0; i < 8; ++i) {
            if (n0 + i >= N_NODES) break;
            const float* xr = x + (size_t)(n0 + i) * 64;
            for (int k = 0; k < 64; ++k) {
                float xs = xr[k];
                acc[0][i] = fmaf(xs, Wl[k][tx], acc[0][i]);
                acc[1][i] = fmaf(xs, Wl[k][64 + tx], acc[1][i]);
                acc[2][i] = fmaf(xs, Wl[k][128 + tx], acc[2][i]);
                acc[3][i] = fmaf(xs, Wl[k][tx3], acc[3][i]);
            }
        }
    }
#pragma unroll
    for (int i = 0; i < 8; ++i) {
        ot[ty * 8 + i][tx] = f2bf(acc[0][i]);
        ot[ty * 8 + i][64 + tx] = f2bf(acc[1][i]);
        ot[ty * 8 + i][128 + tx] = f2bf(acc[2][i]);
        if (tx < 48) ot[ty * 8 + i][192 + tx] = f2bf(acc[3][i]);
    }
    __syncthreads();
    int vrows = N_NODES - n0b; if (vrows > 32) vrows = 32;
    {
        const unsigned int* po = (const unsigned int*)&ot[0][0];
        unsigned int* ph = (unsigned int*)(h + (size_t)n0b * 240);
        int limit = vrows * 120;
        for (int i = tid; i < limit; i += 256) ph[i] = po[i];
    }
    if (tid < 192) {
        int node = tid / 6, hd = tid % 6;
        if (node < vrows) {
            const unsigned short* r = &ot[node][hd * 40];
            const float* as = a_s + hd * 40;
            const float* ad = a_d + hd * 40;
            float s1 = 0.f, s2 = 0.f;
            for (int c = 0; c < 40; c += 2) {
                unsigned int q = *(const unsigned int*)(r + c);
                float2 p = bfp2(q);
                s1 = fmaf(p.x, as[c], s1);     s2 = fmaf(p.x, ad[c], s2);
                s1 = fmaf(p.y, as[c + 1], s1); s2 = fmaf(p.y, ad[c + 1], s2);
            }
            al_s[(n0b + node) * 6 + hd] = s1;
            al_d[(n0b + node) * 6 + hd] = s2;
        }
    }
}

// ---------------- CSR build ----------------
__global__ void deg_kernel(const int* __restrict__ ei, int* __restrict__ deg) {
    int e = blockIdx.x * 256 + threadIdx.x;
    if (e >= N_EDGES) return;
    atomicAdd(&deg[ei[N_EDGES + e]], 1);
}

// 1024 threads; shuffle-based scan (no ladder syncs)
__global__ void scan_kernel(int* __restrict__ deg, int* __restrict__ rowptr) {
    __shared__ int wsum[16];
    const int t = threadIdx.x;
    const int PER = (N_NODES + 1023) / 1024;  // 49
    const int base = t * PER;
    int s = 0;
    for (int i = 0; i < PER; ++i) { int idx = base + i; if (idx < N_NODES) s += deg[idx]; }
    const int lane = t & 63, wv = t >> 6;
    int v = s;
#pragma unroll
    for (int off = 1; off < 64; off <<= 1) {
        int u = __shfl_up(v, off);
        if (lane >= off) v += u;
    }
    if (lane == 63) wsum[wv] = v;
    __syncthreads();
    if (wv == 0 && lane < 16) {
        int u = wsum[lane];
#pragma unroll
        for (int off = 1; off < 16; off <<= 1) {
            int p = __shfl_up(u, off);
            if (lane >= off) u += p;
        }
        wsum[lane] = u;
    }
    __syncthreads();
    int run = v - s + (wv ? wsum[wv - 1] : 0);   // exclusive prefix for this thread
    if (t == 1023) rowptr[N_NODES] = wsum[15];
    for (int i = 0; i < PER; ++i) {
        int idx = base + i;
        if (idx < N_NODES) {
            int d = deg[idx];
            rowptr[idx] = run;
            deg[idx] = run;       // cursor starts at row begin
            run += d;
        }
    }
}

__global__ void scatter_kernel(const int* __restrict__ ei, int* __restrict__ cursor,
                               unsigned short* __restrict__ csr_src) {
    int e = blockIdx.x * 256 + threadIdx.x;
    if (e >= N_EDGES) return;
    int src = ei[e], dst = ei[N_EDGES + e];
    int pos = atomicAdd(&cursor[dst], 1);
    csr_src[pos] = (unsigned short)src;   // N_NODES < 65536
}

// ------- agg layers 1/2 (HC=64): quarter-wave gather -------
// 4 quarters x 16 lanes; quarter q takes edges j = beg+q, beg+q+4, ...
// lane = 4 channels (uint2 = 8B): one instruction = 4 edges x 128B lines.
// cross-quarter reduce via shfl_xor(16,32). Fused bias+ELU epilogue.
__global__ void agg64_kernel(const int* __restrict__ rowptr, const unsigned short* __restrict__ csr_src,
                             const float* __restrict__ al_s, const float* __restrict__ al_d,
                             const unsigned short* __restrict__ hb, const float* __restrict__ b,
                             float* __restrict__ xn) {
    int node = blockIdx.x * 4 + (threadIdx.x >> 6);   // grid exact: N_NODES % 4 == 0
    int lane = threadIdx.x & 63;
    int q = lane >> 4;
    int hl = lane & 15;
    int c0 = hl * 4;
    int hd = hl >> 2;                                 // head = c0/16
    float ald = al_d[node * 4 + hd];
    int beg = rowptr[node], end = rowptr[node + 1];
    float denom = 0.f, a0 = 0.f, a1 = 0.f, a2 = 0.f, a3 = 0.f;
    if (q == 0) {   // self loop on quarter 0
        float w = __expf(lrelu02(al_s[node * 4 + hd] + ald));
        uint2 p = *(const uint2*)(hb + (size_t)node * 64 + c0);
        float2 ab = bfp2(p.x), cd = bfp2(p.y);
        denom = w; a0 = w * ab.x; a1 = w * ab.y; a2 = w * cd.x; a3 = w * cd.y;
    }
    int j = beg + q;
    for (; j + 4 < end; j += 8) {   // 2 edges per quarter = 8 edges per wave iter
        int s0 = csr_src[j], s1 = csr_src[j + 4];
        uint2 p0 = *(const uint2*)(hb + (size_t)s0 * 64 + c0);
        uint2 p1 = *(const uint2*)(hb + (size_t)s1 * 64 + c0);
        float w0 = __expf(lrelu02(al_s[s0 * 4 + hd] + ald));
        float w1 = __expf(lrelu02(al_s[s1 * 4 + hd] + ald));
        denom += w0 + w1;
        float2 u;
        u = bfp2(p0.x); a0 = fmaf(w0, u.x, a0); a1 = fmaf(w0, u.y, a1);
        u = bfp2(p0.y); a2 = fmaf(w0, u.x, a2); a3 = fmaf(w0, u.y, a3);
        u = bfp2(p1.x); a0 = fmaf(w1, u.x, a0); a1 = fmaf(w1, u.y, a1);
        u = bfp2(p1.y); a2 = fmaf(w1, u.x, a2); a3 = fmaf(w1, u.y, a3);
    }
    for (; j < end; j += 4) {
        int s0 = csr_src[j];
        uint2 p0 = *(const uint2*)(hb + (size_t)s0 * 64 + c0);
        float w0 = __expf(lrelu02(al_s[s0 * 4 + hd] + ald));
        denom += w0;
        float2 u;
        u = bfp2(p0.x); a0 = fmaf(w0, u.x, a0); a1 = fmaf(w0, u.y, a1);
        u = bfp2(p0.y); a2 = fmaf(w0, u.x, a2); a3 = fmaf(w0, u.y, a3);
    }
    denom += __shfl_xor(denom, 16); denom += __shfl_xor(denom, 32);
    a0 += __shfl_xor(a0, 16); a0 += __shfl_xor(a0, 32);
    a1 += __shfl_xor(a1, 16); a1 += __shfl_xor(a1, 32);
    a2 += __shfl_xor(a2, 16); a2 += __shfl_xor(a2, 32);
    a3 += __shfl_xor(a3, 16); a3 += __shfl_xor(a3, 32);
    if (q == 0) {
        float r = 1.f / denom;
        float4 o;
        o.x = elu1(a0 * r + b[c0]);
        o.y = elu1(a1 * r + b[c0 + 1]);
        o.z = elu1(a2 * r + b[c0 + 2]);
        o.w = elu1(a3 * r + b[c0 + 3]);
        *(float4*)(xn + (size_t)node * 64 + c0) = o;
    }
}

// ------- agg layer 3 (HC=240): lane = 4 channels; fused final epilogue -------
__global__ void agg240_kernel(const int* __restrict__ rowptr, const unsigned short* __restrict__ csr_src,
                              const float* __restrict__ al_s, const float* __restrict__ al_d,
                              const unsigned short* __restrict__ hb, const float* __restrict__ b3,
                              float* __restrict__ y) {
    __shared__ float sh[4][240];
    int wv_id = threadIdx.x >> 6;
    int node = blockIdx.x * 4 + wv_id;                // grid exact: 12500 blocks
    int lane = threadIdx.x & 63;
    bool act = lane < 60;
    int c0 = act ? lane * 4 : 0;
    int hd = c0 / 40;
    float ald = al_d[node * 6 + hd];
    int beg = rowptr[node], end = rowptr[node + 1];
    float w = __expf(lrelu02(al_s[node * 6 + hd] + ald));
    float denom = w;
    float4 acc;
    {
        uint2 q = *(const uint2*)(hb + (size_t)node * 240 + c0);
        float2 ab = bfp2(q.x), cd = bfp2(q.y);
        acc.x = w * ab.x; acc.y = w * ab.y; acc.z = w * cd.x; acc.w = w * cd.y;
    }
    int j = beg;
    for (; j + 8 <= end; j += 8) {
        int s[8];
        uint2 q[8];
#pragma unroll
        for (int u = 0; u < 8; ++u) s[u] = csr_src[j + u];
#pragma unroll
        for (int u = 0; u < 8; ++u) q[u] = *(const uint2*)(hb + (size_t)s[u] * 240 + c0);
        float wvv[8];
#pragma unroll
        for (int u = 0; u < 8; ++u) wvv[u] = __expf(lrelu02(al_s[s[u] * 6 + hd] + ald));
#pragma unroll
        for (int u = 0; u < 8; ++u) {
            denom += wvv[u];
            float2 ab = bfp2(q[u].x), cd = bfp2(q[u].y);
            acc.x = fmaf(wvv[u], ab.x, acc.x); acc.y = fmaf(wvv[u], ab.y, acc.y);
            acc.z = fmaf(wvv[u], cd.x, acc.z); acc.w = fmaf(wvv[u], cd.y, acc.w);
        }
    }
    for (; j < end; ++j) {
        int s0 = csr_src[j];
        uint2 q0 = *(const uint2*)(hb + (size_t)s0 * 240 + c0);
        float w0 = __expf(lrelu02(al_s[s0 * 6 + hd] + ald));
        denom += w0;
        float2 ab = bfp2(q0.x), cd = bfp2(q0.y);
        acc.x = fmaf(w0, ab.x, acc.x); acc.y = fmaf(w0, ab.y, acc.y);
        acc.z = fmaf(w0, cd.x, acc.z); acc.w = fmaf(w0, cd.y, acc.w);
    }
    if (act) {
        float r = 1.f / denom;
        float* sp = &sh[wv_id][c0];
        sp[0] = acc.x * r; sp[1] = acc.y * r; sp[2] = acc.z * r; sp[3] = acc.w * r;
    }
    __syncthreads();
    float v;
    if (lane < 40) {
        const float* p = sh[wv_id];
        float s = 0.f;
#pragma unroll
        for (int hh = 0; hh < 6; ++hh) s += p[hh * 40 + lane];
        v = elu1(s * (1.f / 6.f) + b3[lane]);
    } else {
        v = -INFINITY;
    }
    float m = v;
#pragma unroll
    for (int o = 32; o > 0; o >>= 1) m = fmaxf(m, __shfl_xor(m, o));
    float ex = (lane < 40) ? __expf(v - m) : 0.f;
    float ssum = ex;
#pragma unroll
    for (int o = 32; o > 0; o >>= 1) ssum += __shfl_xor(ssum, o);
    if (lane < 40) y[(size_t)node * 40 + lane] = v - m - __logf(ssum);
}

extern "C" void kernel_launch(void* const* d_in, const int* in_sizes, int n_in,
                              void* d_out, int out_size, void* d_ws, size_t ws_size,
                              hipStream_t stream) {
    const float* x   = (const float*)d_in[0];
    const int*   ei  = (const int*)d_in[1];   // [2, E]
    const float* W1  = (const float*)d_in[2];
    const float* a1s = (const float*)d_in[3];
    const float* a1d = (const float*)d_in[4];
    const float* b1  = (const float*)d_in[5];
    const float* W2  = (const float*)d_in[6];
    const float* a2s = (const float*)d_in[7];
    const float* a2d = (const float*)d_in[8];
    const float* b2  = (const float*)d_in[9];
    const float* W3  = (const float*)d_in[10];
    const float* a3s = (const float*)d_in[11];
    const float* a3d = (const float*)d_in[12];
    const float* b3  = (const float*)d_in[13];
    float* y = (float*)d_out;

    float* ws      = (float*)d_ws;
    unsigned short* h_bf = (unsigned short*)ws;           // 12,000,000 ushort (= 6.0M floats)
    float* x_buf   = ws + 6000000;                        //  3,200,000
    float* al_s    = ws + 9200000;                        //    300,000
    float* al_d    = ws + 9500000;                        //    300,000
    int*   deg     = (int*)(ws + 9800000);                //     50,000 (becomes cursor)
    int*   rowptr  = (int*)(ws + 9850000);                //     50,001
    unsigned short* csr_src = (unsigned short*)(ws + 9900008); // 1.6M ushort
    // total: 10,700,008 floats = 42.8 MB

    // ---- CSR build (once; shared by all 3 layers) ----
    hipMemsetAsync(deg, 0, N_NODES * sizeof(int), stream);
    deg_kernel<<<(N_EDGES + 255) / 256, 256, 0, stream>>>(ei, deg);
    scan_kernel<<<1, 1024, 0, stream>>>(deg, rowptr);
    scatter_kernel<<<(N_EDGES + 255) / 256, 256, 0, stream>>>(ei, deg, csr_src);

    const int agg_grid = N_NODES / 4;              // 12500, exact
    const int gemm_gx = (N_NODES + 31) / 32;
    dim3 gblk(64, 4);

    // ---- layer 1: 128 -> (4,16) concat ----
    gemm_al_kernel<128><<<gemm_gx, gblk, 0, stream>>>(x, W1, a1s, a1d, h_bf, al_s, al_d);
    agg64_kernel<<<agg_grid, 256, 0, stream>>>(rowptr, csr_src, al_s, al_d, h_bf, b1, x_buf);

    // ---- layer 2: 64 -> (4,16) concat ----
    gemm_al_kernel<64><<<gemm_gx, gblk, 0, stream>>>(x_buf, W2, a2s, a2d, h_bf, al_s, al_d);
    agg64_kernel<<<agg_grid, 256, 0, stream>>>(rowptr, csr_src, al_s, al_d, h_bf, b2, x_buf);

    // ---- layer 3: 64 -> (6,40) mean ----
    gemm240_kernel<<<gemm_gx, gblk, 0, stream>>>(x_buf, W3, a3s, a3d, h_bf, al_s, al_d);
    agg240_kernel<<<agg_grid, 256, 0, stream>>>(rowptr, csr_src, al_s, al_d, h_bf, b3, y);
}

// Round 9
// 724.200 us; speedup vs baseline: 1.0799x; 1.0799x over previous
//
#include <hip/hip_runtime.h>
#include <math.h>

#define N_NODES 50000
#define N_EDGES 1600000
#define NB      391          // ceil(50000/128) buckets of 128 nodes

__device__ __forceinline__ float lrelu02(float x) { return x > 0.f ? x : 0.2f * x; }
__device__ __forceinline__ float elu1(float x)    { return x > 0.f ? x : __expf(x) - 1.f; }

// bf16 helpers (RNE pack)
__device__ __forceinline__ unsigned short f2bf(float f) {
    unsigned int u = __float_as_uint(f);
    return (unsigned short)((u + 0x7fffu + ((u >> 16) & 1u)) >> 16);
}
__device__ __forceinline__ float bf2f(unsigned short s) {
    return __uint_as_float((unsigned int)s << 16);
}
__device__ __forceinline__ float2 bfp2(unsigned int u) {
    float2 r;
    r.x = __uint_as_float(u << 16);
    r.y = __uint_as_float(u & 0xffff0000u);
    return r;
}

// ------- GEMM layers 1/2 (FOUT=64) fused with attention logits -------
template<int FIN>
__global__ void gemm_al_kernel(const float* __restrict__ x, const float* __restrict__ W,
                               const float* __restrict__ a_s, const float* __restrict__ a_d,
                               unsigned short* __restrict__ h,
                               float* __restrict__ al_s, float* __restrict__ al_d) {
    __shared__ float Wl[FIN][64];
    __shared__ unsigned short ot[32][66];   // +2 pad: LDS rows stride 33 dwords
    const int tx = threadIdx.x, ty = threadIdx.y;
    const int tid = ty * 64 + tx;
    for (int i = tid; i < FIN * 64; i += 256) {
        int k = i >> 6, f = i & 63;
        Wl[k][f] = W[(size_t)k * 64 + f];
    }
    __syncthreads();
    const int n0b = blockIdx.x * 32;
    const int n0 = n0b + ty * 8;
    float acc[8] = {0.f, 0.f, 0.f, 0.f, 0.f, 0.f, 0.f, 0.f};
    if (n0 + 8 <= N_NODES) {
        for (int k = 0; k < FIN; k += 4) {
            float4 xv[8];
#pragma unroll
            for (int i = 0; i < 8; ++i)
                xv[i] = *(const float4*)(x + (size_t)(n0 + i) * FIN + k);
#pragma unroll
            for (int kk = 0; kk < 4; ++kk) {
                float w = Wl[k + kk][tx];
#pragma unroll
                for (int i = 0; i < 8; ++i) {
                    float xs = (kk == 0) ? xv[i].x : (kk == 1) ? xv[i].y : (kk == 2) ? xv[i].z : xv[i].w;
                    acc[i] = fmaf(xs, w, acc[i]);
                }
            }
        }
    } else {
        for (int i = 0; i < 8; ++i) {
            if (n0 + i >= N_NODES) break;
            const float* xr = x + (size_t)(n0 + i) * FIN;
            float a = 0.f;
            for (int k = 0; k < FIN; ++k) a = fmaf(xr[k], Wl[k][tx], a);
            acc[i] = a;
        }
    }
#pragma unroll
    for (int i = 0; i < 8; ++i) ot[ty * 8 + i][tx] = f2bf(acc[i]);
    __syncthreads();
    int vrows = N_NODES - n0b; if (vrows > 32) vrows = 32;
    {
        unsigned int* ph = (unsigned int*)(h + (size_t)n0b * 64);
        for (int i = tid; i < vrows * 32; i += 256) {
            int row = i >> 5, col = i & 31;
            ph[i] = *(const unsigned int*)&ot[row][col * 2];
        }
    }
    if (tid < 128) {
        int node = tid >> 2, hd = tid & 3;
        if (node < vrows) {
            const float* as = a_s + hd * 16;
            const float* ad = a_d + hd * 16;
            float s1 = 0.f, s2 = 0.f;
#pragma unroll
            for (int c = 0; c < 16; c += 2) {
                unsigned int q = *(const unsigned int*)&ot[node][hd * 16 + c];
                float2 p = bfp2(q);
                s1 = fmaf(p.x, as[c], s1);     s2 = fmaf(p.x, ad[c], s2);
                s1 = fmaf(p.y, as[c + 1], s1); s2 = fmaf(p.y, ad[c + 1], s2);
            }
            al_s[(n0b + node) * 4 + hd] = s1;
            al_d[(n0b + node) * 4 + hd] = s2;
        }
    }
}

// ------- L3 GEMM: h[n,240] = bf16(x[n,64] @ W[64,240]), fused al3 -------
__global__ void gemm240_kernel(const float* __restrict__ x, const float* __restrict__ W,
                               const float* __restrict__ a_s, const float* __restrict__ a_d,
                               unsigned short* __restrict__ h,
                               float* __restrict__ al_s, float* __restrict__ al_d) {
    __shared__ float Wl[64][240];           // 61440 B
    __shared__ unsigned short ot[32][240];  // 15360 B
    const int tx = threadIdx.x, ty = threadIdx.y;
    const int tid = ty * 64 + tx;
    {
        const float4* W4 = (const float4*)W;
        float4* Wl4 = (float4*)&Wl[0][0];
        for (int i = tid; i < 64 * 240 / 4; i += 256) Wl4[i] = W4[i];
    }
    __syncthreads();
    const int n0b = blockIdx.x * 32;
    const int n0 = n0b + ty * 8;
    float acc[4][8];
#pragma unroll
    for (int g = 0; g < 4; ++g)
#pragma unroll
        for (int i = 0; i < 8; ++i) acc[g][i] = 0.f;
    const int tx3 = (tx < 48) ? (192 + tx) : 0;
    if (n0 + 8 <= N_NODES) {
        for (int k = 0; k < 64; k += 4) {
            float4 xv[8];
#pragma unroll
            for (int i = 0; i < 8; ++i)
                xv[i] = *(const float4*)(x + (size_t)(n0 + i) * 64 + k);
#pragma unroll
            for (int kk = 0; kk < 4; ++kk) {
                float w0 = Wl[k + kk][tx];
                float w1 = Wl[k + kk][64 + tx];
                float w2 = Wl[k + kk][128 + tx];
                float w3 = Wl[k + kk][tx3];
#pragma unroll
                for (int i = 0; i < 8; ++i) {
                    float xs = (kk == 0) ? xv[i].x : (kk == 1) ? xv[i].y : (kk == 2) ? xv[i].z : xv[i].w;
                    acc[0][i] = fmaf(xs, w0, acc[0][i]);
                    acc[1][i] = fmaf(xs, w1, acc[1][i]);
                    acc[2][i] = fmaf(xs, w2, acc[2][i]);
                    acc[3][i] = fmaf(xs, w3, acc[3][i]);
                }
            }
        }
    } else {
        for (int i = 0; i < 8; ++i) {
            if (n0 + i >= N_NODES) break;
            const float* xr = x + (size_t)(n0 + i) * 64;
            for (int k = 0; k < 64; ++k) {
                float xs = xr[k];
                acc[0][i] = fmaf(xs, Wl[k][tx], acc[0][i]);
                acc[1][i] = fmaf(xs, Wl[k][64 + tx], acc[1][i]);
                acc[2][i] = fmaf(xs, Wl[k][128 + tx], acc[2][i]);
                acc[3][i] = fmaf(xs, Wl[k][tx3], acc[3][i]);
            }
        }
    }
#pragma unroll
    for (int i = 0; i < 8; ++i) {
        ot[ty * 8 + i][tx] = f2bf(acc[0][i]);
        ot[ty * 8 + i][64 + tx] = f2bf(acc[1][i]);
        ot[ty * 8 + i][128 + tx] = f2bf(acc[2][i]);
        if (tx < 48) ot[ty * 8 + i][192 + tx] = f2bf(acc[3][i]);
    }
    __syncthreads();
    int vrows = N_NODES - n0b; if (vrows > 32) vrows = 32;
    {
        const unsigned int* po = (const unsigned int*)&ot[0][0];
        unsigned int* ph = (unsigned int*)(h + (size_t)n0b * 240);
        int limit = vrows * 120;
        for (int i = tid; i < limit; i += 256) ph[i] = po[i];
    }
    if (tid < 192) {
        int node = tid / 6, hd = tid % 6;
        if (node < vrows) {
            const unsigned short* r = &ot[node][hd * 40];
            const float* as = a_s + hd * 40;
            const float* ad = a_d + hd * 40;
            float s1 = 0.f, s2 = 0.f;
            for (int c = 0; c < 40; c += 2) {
                unsigned int q = *(const unsigned int*)(r + c);
                float2 p = bfp2(q);
                s1 = fmaf(p.x, as[c], s1);     s2 = fmaf(p.x, ad[c], s2);
                s1 = fmaf(p.y, as[c + 1], s1); s2 = fmaf(p.y, ad[c + 1], s2);
            }
            al_s[(n0b + node) * 6 + hd] = s1;
            al_d[(n0b + node) * 6 + hd] = s2;
        }
    }
}

// ---------------- CSR build ----------------
__global__ void deg_kernel(const int* __restrict__ ei, int* __restrict__ deg) {
    int e = blockIdx.x * 256 + threadIdx.x;
    if (e >= N_EDGES) return;
    atomicAdd(&deg[ei[N_EDGES + e]], 1);
}

// 1024 threads; shuffle-based scan
__global__ void scan_kernel(const int* __restrict__ deg, int* __restrict__ rowptr) {
    __shared__ int wsum[16];
    const int t = threadIdx.x;
    const int PER = (N_NODES + 1023) / 1024;  // 49
    const int base = t * PER;
    int s = 0;
    for (int i = 0; i < PER; ++i) { int idx = base + i; if (idx < N_NODES) s += deg[idx]; }
    const int lane = t & 63, wv = t >> 6;
    int v = s;
#pragma unroll
    for (int off = 1; off < 64; off <<= 1) {
        int u = __shfl_up(v, off);
        if (lane >= off) v += u;
    }
    if (lane == 63) wsum[wv] = v;
    __syncthreads();
    if (wv == 0 && lane < 16) {
        int u = wsum[lane];
#pragma unroll
        for (int off = 1; off < 16; off <<= 1) {
            int p = __shfl_up(u, off);
            if (lane >= off) u += p;
        }
        wsum[lane] = u;
    }
    __syncthreads();
    int run = v - s + (wv ? wsum[wv - 1] : 0);   // exclusive prefix
    if (t == 1023) rowptr[N_NODES] = wsum[15];
    for (int i = 0; i < PER; ++i) {
        int idx = base + i;
        if (idx < N_NODES) {
            rowptr[idx] = run;
            run += deg[idx];
        }
    }
}

// bucket cursors: one per 64B line (16 ints) to avoid same-line atomic serialization
__global__ void initcur_kernel(const int* __restrict__ rowptr, int* __restrict__ bcur) {
    int b = blockIdx.x * 256 + threadIdx.x;
    if (b < NB) bcur[b * 16] = rowptr[b * 128];
}

// pass A: append (dst_low, src) into per-bucket staging region (sequential-filling lines)
__global__ void bucket_kernel(const int* __restrict__ ei, int* __restrict__ bcur,
                              unsigned int* __restrict__ stage) {
    int e = blockIdx.x * 256 + threadIdx.x;
    if (e >= N_EDGES) return;
    int src = ei[e], dst = ei[N_EDGES + e];
    int pos = atomicAdd(&bcur[(dst >> 7) * 16], 1);
    stage[pos] = ((unsigned int)(dst & 127) << 16) | (unsigned int)src;
}

// pass B: one block per bucket; LDS node-cursors; writes land in the bucket's ~8KB window
__global__ void place_kernel(const int* __restrict__ rowptr, const unsigned int* __restrict__ stage,
                             unsigned short* __restrict__ csr) {
    __shared__ int cur[128];
    const int b = blockIdx.x;
    const int n0 = b * 128;
    const int t = threadIdx.x;
    if (t < 128) {
        int n = n0 + t;
        cur[t] = (n < N_NODES) ? rowptr[n] : 0;
    }
    __syncthreads();
    int beg = rowptr[n0];
    int nend = n0 + 128; if (nend > N_NODES) nend = N_NODES;
    int end = rowptr[nend];
    for (int i = beg + t; i < end; i += 256) {
        unsigned int v = stage[i];
        int pos = atomicAdd(&cur[v >> 16], 1);
        csr[pos] = (unsigned short)(v & 0xFFFFu);
    }
}

// ------- agg layers 1/2 (HC=64): dual-edge half-wave gather (R7 form) -------
__global__ void agg64_kernel(const int* __restrict__ rowptr, const unsigned short* __restrict__ csr_src,
                             const float* __restrict__ al_s, const float* __restrict__ al_d,
                             const unsigned short* __restrict__ hb, const float* __restrict__ b,
                             float* __restrict__ xn) {
    int node = blockIdx.x * 4 + (threadIdx.x >> 6);   // grid exact: N_NODES % 4 == 0
    int lane = threadIdx.x & 63;
    int half = lane >> 5;
    int hl = lane & 31;
    int c0 = hl * 2;
    int hd = hl >> 3;                                 // head = (2*hl)/16
    float ald = al_d[node * 4 + hd];
    int beg = rowptr[node], end = rowptr[node + 1];
    float denom = 0.f, a0 = 0.f, a1 = 0.f;
    if (half == 0) {   // self loop on half 0
        float w = __expf(lrelu02(al_s[node * 4 + hd] + ald));
        float2 p = bfp2(*(const unsigned int*)(hb + (size_t)node * 64 + c0));
        denom = w; a0 = w * p.x; a1 = w * p.y;
    }
    int j = beg + half;
    for (; j + 6 < end; j += 8) {   // 4 edges per half = 8 edges per wave
        int s0 = csr_src[j], s1 = csr_src[j + 2], s2 = csr_src[j + 4], s3 = csr_src[j + 6];
        unsigned int q0 = *(const unsigned int*)(hb + (size_t)s0 * 64 + c0);
        unsigned int q1 = *(const unsigned int*)(hb + (size_t)s1 * 64 + c0);
        unsigned int q2 = *(const unsigned int*)(hb + (size_t)s2 * 64 + c0);
        unsigned int q3 = *(const unsigned int*)(hb + (size_t)s3 * 64 + c0);
        float w0 = __expf(lrelu02(al_s[s0 * 4 + hd] + ald));
        float w1 = __expf(lrelu02(al_s[s1 * 4 + hd] + ald));
        float w2 = __expf(lrelu02(al_s[s2 * 4 + hd] + ald));
        float w3 = __expf(lrelu02(al_s[s3 * 4 + hd] + ald));
        denom += (w0 + w1) + (w2 + w3);
        float2 p;
        p = bfp2(q0); a0 = fmaf(w0, p.x, a0); a1 = fmaf(w0, p.y, a1);
        p = bfp2(q1); a0 = fmaf(w1, p.x, a0); a1 = fmaf(w1, p.y, a1);
        p = bfp2(q2); a0 = fmaf(w2, p.x, a0); a1 = fmaf(w2, p.y, a1);
        p = bfp2(q3); a0 = fmaf(w3, p.x, a0); a1 = fmaf(w3, p.y, a1);
    }
    for (; j < end; j += 2) {
        int s0 = csr_src[j];
        unsigned int q0 = *(const unsigned int*)(hb + (size_t)s0 * 64 + c0);
        float w0 = __expf(lrelu02(al_s[s0 * 4 + hd] + ald));
        denom += w0;
        float2 p = bfp2(q0);
        a0 = fmaf(w0, p.x, a0); a1 = fmaf(w0, p.y, a1);
    }
    denom += __shfl_xor(denom, 32);
    a0 += __shfl_xor(a0, 32);
    a1 += __shfl_xor(a1, 32);
    if (half == 0) {
        float2 o;
        o.x = elu1(a0 / denom + b[c0]);
        o.y = elu1(a1 / denom + b[c0 + 1]);
        *(float2*)(xn + (size_t)node * 64 + c0) = o;
    }
}

// ------- agg layer 3 (HC=240): lane = 4 channels; fused final epilogue -------
__global__ void agg240_kernel(const int* __restrict__ rowptr, const unsigned short* __restrict__ csr_src,
                              const float* __restrict__ al_s, const float* __restrict__ al_d,
                              const unsigned short* __restrict__ hb, const float* __restrict__ b3,
                              float* __restrict__ y) {
    __shared__ float sh[4][240];
    int wv_id = threadIdx.x >> 6;
    int node = blockIdx.x * 4 + wv_id;                // grid exact: 12500 blocks
    int lane = threadIdx.x & 63;
    bool act = lane < 60;
    int c0 = act ? lane * 4 : 0;
    int hd = c0 / 40;
    float ald = al_d[node * 6 + hd];
    int beg = rowptr[node], end = rowptr[node + 1];
    float w = __expf(lrelu02(al_s[node * 6 + hd] + ald));
    float denom = w;
    float4 acc;
    {
        uint2 q = *(const uint2*)(hb + (size_t)node * 240 + c0);
        float2 ab = bfp2(q.x), cd = bfp2(q.y);
        acc.x = w * ab.x; acc.y = w * ab.y; acc.z = w * cd.x; acc.w = w * cd.y;
    }
    int j = beg;
    for (; j + 8 <= end; j += 8) {
        int s[8];
        uint2 q[8];
#pragma unroll
        for (int u = 0; u < 8; ++u) s[u] = csr_src[j + u];
#pragma unroll
        for (int u = 0; u < 8; ++u) q[u] = *(const uint2*)(hb + (size_t)s[u] * 240 + c0);
        float wvv[8];
#pragma unroll
        for (int u = 0; u < 8; ++u) wvv[u] = __expf(lrelu02(al_s[s[u] * 6 + hd] + ald));
#pragma unroll
        for (int u = 0; u < 8; ++u) {
            denom += wvv[u];
            float2 ab = bfp2(q[u].x), cd = bfp2(q[u].y);
            acc.x = fmaf(wvv[u], ab.x, acc.x); acc.y = fmaf(wvv[u], ab.y, acc.y);
            acc.z = fmaf(wvv[u], cd.x, acc.z); acc.w = fmaf(wvv[u], cd.y, acc.w);
        }
    }
    for (; j < end; ++j) {
        int s0 = csr_src[j];
        uint2 q0 = *(const uint2*)(hb + (size_t)s0 * 240 + c0);
        float w0 = __expf(lrelu02(al_s[s0 * 6 + hd] + ald));
        denom += w0;
        float2 ab = bfp2(q0.x), cd = bfp2(q0.y);
        acc.x = fmaf(w0, ab.x, acc.x); acc.y = fmaf(w0, ab.y, acc.y);
        acc.z = fmaf(w0, cd.x, acc.z); acc.w = fmaf(w0, cd.y, acc.w);
    }
    if (act) {
        float r = 1.f / denom;
        float* sp = &sh[wv_id][c0];
        sp[0] = acc.x * r; sp[1] = acc.y * r; sp[2] = acc.z * r; sp[3] = acc.w * r;
    }
    __syncthreads();
    float v;
    if (lane < 40) {
        const float* p = sh[wv_id];
        float s = 0.f;
#pragma unroll
        for (int hh = 0; hh < 6; ++hh) s += p[hh * 40 + lane];
        v = elu1(s * (1.f / 6.f) + b3[lane]);
    } else {
        v = -INFINITY;
    }
    float m = v;
#pragma unroll
    for (int o = 32; o > 0; o >>= 1) m = fmaxf(m, __shfl_xor(m, o));
    float ex = (lane < 40) ? __expf(v - m) : 0.f;
    float ssum = ex;
#pragma unroll
    for (int o = 32; o > 0; o >>= 1) ssum += __shfl_xor(ssum, o);
    if (lane < 40) y[(size_t)node * 40 + lane] = v - m - __logf(ssum);
}

extern "C" void kernel_launch(void* const* d_in, const int* in_sizes, int n_in,
                              void* d_out, int out_size, void* d_ws, size_t ws_size,
                              hipStream_t stream) {
    const float* x   = (const float*)d_in[0];
    const int*   ei  = (const int*)d_in[1];   // [2, E]
    const float* W1  = (const float*)d_in[2];
    const float* a1s = (const float*)d_in[3];
    const float* a1d = (const float*)d_in[4];
    const float* b1  = (const float*)d_in[5];
    const float* W2  = (const float*)d_in[6];
    const float* a2s = (const float*)d_in[7];
    const float* a2d = (const float*)d_in[8];
    const float* b2  = (const float*)d_in[9];
    const float* W3  = (const float*)d_in[10];
    const float* a3s = (const float*)d_in[11];
    const float* a3d = (const float*)d_in[12];
    const float* b3  = (const float*)d_in[13];
    float* y = (float*)d_out;

    float* ws      = (float*)d_ws;
    unsigned short* h_bf = (unsigned short*)ws;           // 12,000,000 ushort
    float* x_buf   = ws + 6000000;                        //  3,200,000
    float* al_s    = ws + 9200000;                        //    300,000
    float* al_d    = ws + 9500000;                        //    300,000
    int*   deg     = (int*)(ws + 9800000);                //     50,000
    int*   rowptr  = (int*)(ws + 9850000);                //     50,001
    unsigned short* csr_src = (unsigned short*)(ws + 9900008); // 1.6M ushort = 800,000 floats
    unsigned int* stage = (unsigned int*)(ws + 10700008); // 1.6M uint
    int* bcur = (int*)(ws + 12300008);                    // NB*16 ints (64B-strided cursors)
    // total ~12,306,264 floats = 49.2 MB

    // ---- CSR build via bucketed counting sort (once; shared by all 3 layers) ----
    hipMemsetAsync(deg, 0, N_NODES * sizeof(int), stream);
    deg_kernel<<<(N_EDGES + 255) / 256, 256, 0, stream>>>(ei, deg);
    scan_kernel<<<1, 1024, 0, stream>>>(deg, rowptr);
    initcur_kernel<<<(NB + 255) / 256, 256, 0, stream>>>(rowptr, bcur);
    bucket_kernel<<<(N_EDGES + 255) / 256, 256, 0, stream>>>(ei, bcur, stage);
    place_kernel<<<NB, 256, 0, stream>>>(rowptr, stage, csr_src);

    const int agg_grid = N_NODES / 4;              // 12500, exact
    const int gemm_gx = (N_NODES + 31) / 32;
    dim3 gblk(64, 4);

    // ---- layer 1: 128 -> (4,16) concat ----
    gemm_al_kernel<128><<<gemm_gx, gblk, 0, stream>>>(x, W1, a1s, a1d, h_bf, al_s, al_d);
    agg64_kernel<<<agg_grid, 256, 0, stream>>>(rowptr, csr_src, al_s, al_d, h_bf, b1, x_buf);

    // ---- layer 2: 64 -> (4,16) concat ----
    gemm_al_kernel<64><<<gemm_gx, gblk, 0, stream>>>(x_buf, W2, a2s, a2d, h_bf, al_s, al_d);
    agg64_kernel<<<agg_grid, 256, 0, stream>>>(rowptr, csr_src, al_s, al_d, h_bf, b2, x_buf);

    // ---- layer 3: 64 -> (6,40) mean ----
    gemm240_kernel<<<gemm_gx, gblk, 0, stream>>>(x_buf, W3, a3s, a3d, h_bf, al_s, al_d);
    agg240_kernel<<<agg_grid, 256, 0, stream>>>(rowptr, csr_src, al_s, al_d, h_bf, b3, y);
}